// Round 1
// baseline (635.836 us; speedup 1.0000x reference)
//
#include <hip/hip_runtime.h>
#include <hip/hip_bf16.h>

#define NTOK 49
#define DIM  128
#define NH   4
#define HD   32
#define NWIN 8192
#define NWM  64

typedef short short8 __attribute__((ext_vector_type(8)));
typedef float f32x4  __attribute__((ext_vector_type(4)));

// HW RNE f32->bf16: plain cast lets hipcc emit v_cvt_pk_bf16_f32 (1 op / 2 elems)
// vs the old 4-op manual round (was ~1280 VALU ops/lane total).
__device__ __forceinline__ short f2bf(float f) {
  return __builtin_bit_cast(short, __float2bfloat16(f));
}

__global__ void prep_weights(const float* __restrict__ qkv_w,
                             const float* __restrict__ proj_w,
                             short* __restrict__ wq, short* __restrict__ wp) {
  int i = blockIdx.x * 256 + threadIdx.x;            // grid covers 49152+16384 exactly
  if (i < 3 * DIM * DIM) wq[i] = f2bf(qkv_w[i]);
  else wp[i - 3 * DIM * DIM] = f2bf(proj_w[i - 3 * DIM * DIM]);
}

__global__ void prep_bm(const float* __restrict__ attn_mask,
                        const float* __restrict__ rpb_table,
                        const int* __restrict__ rpb_index,
                        float* __restrict__ bm) {
  int wm = blockIdx.x >> 2, h = blockIdx.x & 3;      // 256 blocks = 64 masks x 4 heads
  const float* mrow = attn_mask + wm * (NTOK * NTOK);
  float* dst = bm + blockIdx.x * (NTOK * NTOK);
  for (int i = threadIdx.x; i < NTOK * NTOK; i += 256)
    dst[i] = rpb_table[rpb_index[i] * NH + h] + mrow[i];
}

// LDS layout (53248 B total -> 3 blocks/CU; was 59392 -> 2 blocks/CU):
//   [0, 36864): 4 per-head regions of 9216B:
//       Q [64 rows][64B]  swizzled (slot ^= (row>>1)&3)   at +0    (4096B)
//       K same                                            at +4096 (4096B)
//       P [64 rows][144B] (stride 72 shorts, known conflict-ok) OVERLAYS Q/K
//         after S is done (same wave, in-order LDS).
//   [36864, 53248): Vt per head [32 rows(d)][128B] swizzled (slot ^= d&7), 4096B each.
//   Y [64][272B] (17408B) OVERLAYS head regions (barrier-protected).
#define HREG 9216
#define KOFF 4096
#define VOFF 36864
#define VSZ  4096
#define P_STRIDE 144
#define Y_STRIDE 272
#define LDS_BYTES 53248

// Q/K byte offset: row stride 64B, 4x16B slots, XOR swizzle -> b128 reads are 2-way max.
__device__ __forceinline__ int qk_off(int m, int d) {
  return m * 64 + ((((d >> 3) ^ (m >> 1)) & 3) << 4) + (d & 7) * 2;
}
// Vt byte offset: row = channel d (32 rows, 128B), col = token m, 8x16B slots, XOR swizzle.
__device__ __forceinline__ int vt_off(int d, int m) {
  return d * 128 + ((((m >> 3) ^ d) & 7) << 4) + (m & 7) * 2;
}

template<bool USE_BM>
__global__ void __launch_bounds__(256, 3)
swin_attn(const float* __restrict__ x,
          const short* __restrict__ wq, const short* __restrict__ wp,
          const float* __restrict__ qkv_b, const float* __restrict__ proj_b,
          const float* __restrict__ bm,
          const int* __restrict__ rpb_index, const float* __restrict__ rpb_table,
          const float* __restrict__ attn_mask,
          float* __restrict__ out) {
  __shared__ __align__(16) char smem[LDS_BYTES];
  const int w    = blockIdx.x;
  const int tid  = threadIdx.x;
  const int h    = tid >> 6;          // wave id == head id
  const int lane = tid & 63;
  const int l16  = lane & 15;
  const int quad = lane >> 4;

  char* qb = smem + h * HREG;
  char* kb = qb + KOFF;
  char* pb = qb;                      // P overlays Q/K (same wave, in-order LDS)
  char* vb = smem + VOFF + h * VSZ;
  char* yb = smem;                    // Y overlays head regions (barrier-protected)

  // ---- phase 0: x A-fragments (global -> regs, fp32 -> bf16) ----
  short8 af[4][4];
  const float* xw = x + (size_t)w * (NTOK * DIM);
  #pragma unroll
  for (int mt = 0; mt < 4; ++mt) {
    int row = mt * 16 + l16; if (row > 48) row = 48;  // clamp pad rows (finite garbage, never stored)
    #pragma unroll
    for (int ks = 0; ks < 4; ++ks) {
      const f32x4* p = (const f32x4*)(xw + row * DIM + ks * 32 + quad * 8);
      f32x4 f0 = p[0], f1 = p[1];
      short8 a;
      a[0]=f2bf(f0[0]); a[1]=f2bf(f0[1]); a[2]=f2bf(f0[2]); a[3]=f2bf(f0[3]);
      a[4]=f2bf(f1[0]); a[5]=f2bf(f1[1]); a[6]=f2bf(f1[2]); a[7]=f2bf(f1[3]);
      af[mt][ks] = a;
    }
  }

  const float scale = 0.17677669529663687f;  // 32^-0.5, folded into Q

  // ---- phase 1: QKV GEMM. chunk c: 0=Q,1=K,2=V; wave h handles channels c*128+h*32..+32 ----
  #pragma unroll
  for (int c = 0; c < 3; ++c) {
    const int o0 = c * DIM + h * HD;
    f32x4 acc[2][4];
    #pragma unroll
    for (int nt = 0; nt < 2; ++nt)
      #pragma unroll
      for (int mt = 0; mt < 4; ++mt) { f32x4 z = {0.f,0.f,0.f,0.f}; acc[nt][mt] = z; }
    #pragma unroll
    for (int ks = 0; ks < 4; ++ks) {
      short8 b0 = *(const short8*)(wq + (o0 + l16) * DIM + ks * 32 + quad * 8);
      short8 b1 = *(const short8*)(wq + (o0 + 16 + l16) * DIM + ks * 32 + quad * 8);
      #pragma unroll
      for (int mt = 0; mt < 4; ++mt) {
        acc[0][mt] = __builtin_amdgcn_mfma_f32_16x16x32_bf16(af[mt][ks], b0, acc[0][mt], 0, 0, 0);
        acc[1][mt] = __builtin_amdgcn_mfma_f32_16x16x32_bf16(af[mt][ks], b1, acc[1][mt], 0, 0, 0);
      }
    }
    #pragma unroll
    for (int nt = 0; nt < 2; ++nt) {
      float bias = qkv_b[o0 + nt * 16 + l16];
      #pragma unroll
      for (int mt = 0; mt < 4; ++mt)
        #pragma unroll
        for (int r = 0; r < 4; ++r) {
          int m = mt * 16 + quad * 4 + r;           // token (C-layout row)
          int d = nt * 16 + l16;                    // hd channel (C-layout col)
          float v = acc[nt][mt][r] + bias;
          if (c == 0)      *(short*)(qb + qk_off(m, d)) = f2bf(v * scale);
          else if (c == 1) *(short*)(kb + qk_off(m, d)) = f2bf(v);
          else             *(short*)(vb + vt_off(d, m)) = f2bf(v);   // V transposed
        }
    }
  }

  // ---- phase 2: S = Q K^T (K-dim = 32 -> single MFMA k-step) ----
  f32x4 s[4][4];
  #pragma unroll
  for (int mt = 0; mt < 4; ++mt)
    #pragma unroll
    for (int nt = 0; nt < 4; ++nt) { f32x4 z = {0.f,0.f,0.f,0.f}; s[mt][nt] = z; }
  {
    short8 aQ[4], bK[4];
    #pragma unroll
    for (int mt = 0; mt < 4; ++mt) {
      int row = mt * 16 + l16;
      aQ[mt] = *(const short8*)(qb + row * 64 + (((quad ^ (row >> 1)) & 3) << 4));
    }
    #pragma unroll
    for (int nt = 0; nt < 4; ++nt) {
      int row = nt * 16 + l16;
      bK[nt] = *(const short8*)(kb + row * 64 + (((quad ^ (row >> 1)) & 3) << 4));
    }
    #pragma unroll
    for (int mt = 0; mt < 4; ++mt)
      #pragma unroll
      for (int nt = 0; nt < 4; ++nt)
        s[mt][nt] = __builtin_amdgcn_mfma_f32_16x16x32_bf16(aQ[mt], bK[nt], s[mt][nt], 0, 0, 0);
  }

  // ---- softmax (in-register, rows live across 16-lane groups) ----
  const int wm = w & (NWM - 1);
  const float* bmh = USE_BM ? bm + (size_t)(wm * NH + h) * (NTOK * NTOK) : nullptr;
  float rinv[4][4];
  #pragma unroll
  for (int mt = 0; mt < 4; ++mt) {
    #pragma unroll
    for (int r = 0; r < 4; ++r) {
      int m = mt * 16 + quad * 4 + r;
      #pragma unroll
      for (int nt = 0; nt < 4; ++nt) {
        int n = nt * 16 + l16;
        float v = s[mt][nt][r];
        if (n >= NTOK) v = -1e30f;                  // pad key columns -> P = 0
        else if (m < NTOK) {
          if (USE_BM) v += bmh[m * NTOK + n];
          else v += rpb_table[rpb_index[m * NTOK + n] * NH + h]
                  + attn_mask[(wm * NTOK + m) * NTOK + n];
        }
        s[mt][nt][r] = v;
      }
      float mx = fmaxf(fmaxf(s[mt][0][r], s[mt][1][r]), fmaxf(s[mt][2][r], s[mt][3][r]));
      mx = fmaxf(mx, __shfl_xor(mx, 1, 16));
      mx = fmaxf(mx, __shfl_xor(mx, 2, 16));
      mx = fmaxf(mx, __shfl_xor(mx, 4, 16));
      mx = fmaxf(mx, __shfl_xor(mx, 8, 16));
      float t = 0.f;
      #pragma unroll
      for (int nt = 0; nt < 4; ++nt) {
        float p = __expf(s[mt][nt][r] - mx);
        s[mt][nt][r] = p;
        t += p;
      }
      t += __shfl_xor(t, 1, 16);
      t += __shfl_xor(t, 2, 16);
      t += __shfl_xor(t, 4, 16);
      t += __shfl_xor(t, 8, 16);
      rinv[mt][r] = __builtin_amdgcn_rcpf(t);       // v_rcp_f32: ~2^-22 rel err, tol is 1.6e-2
      #pragma unroll
      for (int nt = 0; nt < 4; ++nt)
        *(short*)(pb + m * P_STRIDE + (nt * 16 + l16) * 2) = f2bf(s[mt][nt][r]);  // unnormalized P (<=1)
    }
  }

  // ---- phase 3: Y = P V  (K-dim = 64 tokens -> 2 k-steps) ----
  f32x4 y[2][4];
  #pragma unroll
  for (int dt = 0; dt < 2; ++dt)
    #pragma unroll
    for (int mt = 0; mt < 4; ++mt) { f32x4 z = {0.f,0.f,0.f,0.f}; y[dt][mt] = z; }
  #pragma unroll
  for (int kt = 0; kt < 2; ++kt) {
    short8 aP[4], bV[2];
    #pragma unroll
    for (int mt = 0; mt < 4; ++mt)
      aP[mt] = *(const short8*)(pb + (mt * 16 + l16) * P_STRIDE + kt * 64 + quad * 16);
    #pragma unroll
    for (int dt = 0; dt < 2; ++dt) {
      int row = dt * 16 + l16;
      bV[dt] = *(const short8*)(vb + row * 128 + ((((kt * 4 + quad) ^ row) & 7) << 4));
    }
    #pragma unroll
    for (int dt = 0; dt < 2; ++dt)
      #pragma unroll
      for (int mt = 0; mt < 4; ++mt)
        y[dt][mt] = __builtin_amdgcn_mfma_f32_16x16x32_bf16(aP[mt], bV[dt], y[dt][mt], 0, 0, 0);
  }
  #pragma unroll
  for (int dt = 0; dt < 2; ++dt)
    #pragma unroll
    for (int mt = 0; mt < 4; ++mt)
      #pragma unroll
      for (int r = 0; r < 4; ++r)
        y[dt][mt][r] *= rinv[mt][r];                // softmax denominator

  __syncthreads();   // all P reads done before Y overlays the head-buf region
  #pragma unroll
  for (int dt = 0; dt < 2; ++dt)
    #pragma unroll
    for (int mt = 0; mt < 4; ++mt)
      #pragma unroll
      for (int r = 0; r < 4; ++r) {
        int m = mt * 16 + quad * 4 + r;
        *(short*)(yb + m * Y_STRIDE + (h * HD + dt * 16 + l16) * 2) = f2bf(y[dt][mt][r]);
      }
  __syncthreads();   // Y complete before proj reads it cross-wave

  // ---- phase 4: out = Y proj_w^T + proj_b; wave h handles out cols [32h, 32h+32) ----
  {
    const int o0 = h * 32;
    f32x4 oa[2][4];
    #pragma unroll
    for (int nt = 0; nt < 2; ++nt)
      #pragma unroll
      for (int mt = 0; mt < 4; ++mt) { f32x4 z = {0.f,0.f,0.f,0.f}; oa[nt][mt] = z; }
    #pragma unroll
    for (int ks = 0; ks < 4; ++ks) {
      short8 aY[4];
      #pragma unroll
      for (int mt = 0; mt < 4; ++mt)
        aY[mt] = *(const short8*)(yb + (mt * 16 + l16) * Y_STRIDE + ks * 64 + quad * 16);
      short8 b0 = *(const short8*)(wp + (o0 + l16) * DIM + ks * 32 + quad * 8);
      short8 b1 = *(const short8*)(wp + (o0 + 16 + l16) * DIM + ks * 32 + quad * 8);
      #pragma unroll
      for (int mt = 0; mt < 4; ++mt) {
        oa[0][mt] = __builtin_amdgcn_mfma_f32_16x16x32_bf16(aY[mt], b0, oa[0][mt], 0, 0, 0);
        oa[1][mt] = __builtin_amdgcn_mfma_f32_16x16x32_bf16(aY[mt], b1, oa[1][mt], 0, 0, 0);
      }
    }
    float pb0 = proj_b[o0 + l16], pb1 = proj_b[o0 + 16 + l16];
    float* ow = out + (size_t)w * (NTOK * DIM);
    #pragma unroll
    for (int nt = 0; nt < 2; ++nt) {
      float pbv = nt ? pb1 : pb0;
      #pragma unroll
      for (int mt = 0; mt < 4; ++mt)
        #pragma unroll
        for (int r = 0; r < 4; ++r) {
          int m = mt * 16 + quad * 4 + r;
          if (m < NTOK) ow[m * DIM + o0 + nt * 16 + l16] = oa[nt][mt][r] + pbv;
        }
    }
  }
}

extern "C" void kernel_launch(void* const* d_in, const int* in_sizes, int n_in,
                              void* d_out, int out_size, void* d_ws, size_t ws_size,
                              hipStream_t stream) {
  const float* x         = (const float*)d_in[0];
  const float* attn_mask = (const float*)d_in[1];
  const float* qkv_w     = (const float*)d_in[2];
  const float* qkv_b     = (const float*)d_in[3];
  const float* proj_w    = (const float*)d_in[4];
  const float* proj_b    = (const float*)d_in[5];
  const float* rpb_table = (const float*)d_in[6];
  const int*   rpb_index = (const int*)d_in[7];
  float* out = (float*)d_out;

  short* wq = (short*)d_ws;                          // 49152 bf16
  short* wp = wq + 3 * DIM * DIM;                    // 16384 bf16
  float* bmp = (float*)((char*)d_ws + 131072);       // fused bias+mask [64][4][49][49] f32
  size_t need = 131072 + (size_t)NWM * NH * NTOK * NTOK * sizeof(float);

  prep_weights<<<256, 256, 0, stream>>>(qkv_w, proj_w, wq, wp);
  if (ws_size >= need) {
    prep_bm<<<256, 256, 0, stream>>>(attn_mask, rpb_table, rpb_index, bmp);
    swin_attn<true><<<NWIN, 256, 0, stream>>>(x, wq, wp, qkv_b, proj_b, bmp,
                                              rpb_index, rpb_table, attn_mask, out);
  } else {
    swin_attn<false><<<NWIN, 256, 0, stream>>>(x, wq, wp, qkv_b, proj_b, nullptr,
                                               rpb_index, rpb_table, attn_mask, out);
  }
}

// Round 2
// 529.750 us; speedup vs baseline: 1.2003x; 1.2003x over previous
//
#include <hip/hip_runtime.h>
#include <hip/hip_bf16.h>

#define NTOK 49
#define DIM  128
#define NH   4
#define HD   32
#define NWIN 8192
#define NWM  64

typedef short short8 __attribute__((ext_vector_type(8)));
typedef float f32x4  __attribute__((ext_vector_type(4)));

// HW RNE f32->bf16 (hipcc emits v_cvt_pk_bf16_f32 for pairs).
__device__ __forceinline__ short f2bf(float f) {
  return __builtin_bit_cast(short, __float2bfloat16(f));
}

__global__ void prep_weights(const float* __restrict__ qkv_w,
                             const float* __restrict__ proj_w,
                             short* __restrict__ wq, short* __restrict__ wp) {
  int i = blockIdx.x * 256 + threadIdx.x;            // grid covers 49152+16384 exactly
  if (i < 3 * DIM * DIM) wq[i] = f2bf(qkv_w[i]);
  else wp[i - 3 * DIM * DIM] = f2bf(proj_w[i - 3 * DIM * DIM]);
}

__global__ void prep_bm(const float* __restrict__ attn_mask,
                        const float* __restrict__ rpb_table,
                        const int* __restrict__ rpb_index,
                        float* __restrict__ bm) {
  int wm = blockIdx.x >> 2, h = blockIdx.x & 3;      // 256 blocks = 64 masks x 4 heads
  const float* mrow = attn_mask + wm * (NTOK * NTOK);
  float* dst = bm + blockIdx.x * (NTOK * NTOK);
  for (int i = threadIdx.x; i < NTOK * NTOK; i += 256)
    dst[i] = rpb_table[rpb_index[i] * NH + h] + mrow[i];
}

// LDS layout (49152 B total -> 3 blocks/CU; no register af[] -> no spills):
//   [0,     16384): A  [64 rows][256B]  x as bf16, swizzled. Rows 0-48 written;
//                   reads clamp row>48 -> 48.  OVERLAID by V[4 heads][4096B]
//                   ([32 d][128B] transposed, swizzled) after the c==2 barrier.
//   [16384, 32768): Q  [4 heads][64 rows][64B] swizzled.  OVERLAID by P rows 0-31
//                   ([32 m][128B] per head) after phase 2 (same-wave, in-order LDS).
//   [32768, 49152): K  [4 heads][64 rows][64B] swizzled.  OVERLAID by P rows 32-63,
//                   then by Y [64 rows][256B] (barrier-protected).
#define A_BASE 0
#define Q_BASE 16384
#define K_BASE 32768
#define LDS_BYTES 49152

// stride 256B, 16 slots of 16B; lanes read 16 different rows at same slot -> 2-way max
__device__ __forceinline__ int aswz(int row, int slot) {
  return row * 256 + (((slot ^ (row & 7)) & 15) << 4);
}
// stride 64B, 4 slots of 16B
__device__ __forceinline__ int qkswz(int m, int slot) {
  return m * 64 + (((slot ^ ((m >> 1) & 3)) & 3) << 4);
}
// stride 128B, 8 slots of 16B (used by P and V-transposed)
__device__ __forceinline__ int pvswz(int m, int slot) {
  return m * 128 + (((slot ^ (m & 7)) & 7) << 4);
}

template<bool USE_BM>
__global__ void __launch_bounds__(256, 3)
swin_attn(const float* __restrict__ x,
          const short* __restrict__ wq, const short* __restrict__ wp,
          const float* __restrict__ qkv_b, const float* __restrict__ proj_b,
          const float* __restrict__ bm,
          const int* __restrict__ rpb_index, const float* __restrict__ rpb_table,
          const float* __restrict__ attn_mask,
          float* __restrict__ out) {
  __shared__ __align__(16) char smem[LDS_BYTES];
  const int w    = blockIdx.x;
  const int tid  = threadIdx.x;
  const int h    = tid >> 6;          // wave id == head id
  const int lane = tid & 63;
  const int l16  = lane & 15;
  const int quad = lane >> 4;

  char* ab = smem + A_BASE;
  char* qh = smem + Q_BASE + h * 4096;
  char* kh = smem + K_BASE + h * 4096;
  char* vb = smem + A_BASE + h * 4096;     // V overlays A (after c==2 barrier)
  char* yb = smem + K_BASE;                // Y overlays K / P-hi (barrier-protected)
  char* plo = qh;                          // P rows 0-31 overlay Q[h]
  char* phi = kh - 32 * 128;               // P rows 32-63 overlay K[h] (phi + m*128)

  // ---- phase 0: cooperative x -> LDS bf16 (49 rows x 16 8-elem units = 784) ----
  const float* xw = x + (size_t)w * (NTOK * DIM);
  #pragma unroll
  for (int it = 0; it < 4; ++it) {
    int u = tid + it * 256;
    if (u < NTOK * 16) {
      int row = u >> 4, c8 = u & 15;
      const f32x4* p = (const f32x4*)(xw + row * DIM + c8 * 8);
      f32x4 f0 = p[0], f1 = p[1];
      short8 a;
      a[0]=f2bf(f0[0]); a[1]=f2bf(f0[1]); a[2]=f2bf(f0[2]); a[3]=f2bf(f0[3]);
      a[4]=f2bf(f1[0]); a[5]=f2bf(f1[1]); a[6]=f2bf(f1[2]); a[7]=f2bf(f1[3]);
      *(short8*)(ab + aswz(row, c8)) = a;
    }
  }
  __syncthreads();

  const float scale = 0.17677669529663687f;  // 32^-0.5, folded into Q

  // ---- phase 1: QKV GEMM. chunk c: 0=Q,1=K,2=V; wave h handles channels c*128+h*32..+32 ----
  #pragma unroll
  for (int c = 0; c < 3; ++c) {
    const int o0 = c * DIM + h * HD;
    f32x4 acc[2][4];
    #pragma unroll
    for (int nt = 0; nt < 2; ++nt)
      #pragma unroll
      for (int mt = 0; mt < 4; ++mt) { f32x4 z = {0.f,0.f,0.f,0.f}; acc[nt][mt] = z; }
    #pragma unroll
    for (int ks = 0; ks < 4; ++ks) {
      short8 b0 = *(const short8*)(wq + (o0 + l16) * DIM + ks * 32 + quad * 8);
      short8 b1 = *(const short8*)(wq + (o0 + 16 + l16) * DIM + ks * 32 + quad * 8);
      short8 aA[4];
      #pragma unroll
      for (int mt = 0; mt < 4; ++mt) {
        int row = mt * 16 + l16; if (row > 48) row = 48;   // A rows 49-63 never written
        aA[mt] = *(const short8*)(ab + aswz(row, ks * 4 + quad));
      }
      #pragma unroll
      for (int mt = 0; mt < 4; ++mt) {
        acc[0][mt] = __builtin_amdgcn_mfma_f32_16x16x32_bf16(aA[mt], b0, acc[0][mt], 0, 0, 0);
        acc[1][mt] = __builtin_amdgcn_mfma_f32_16x16x32_bf16(aA[mt], b1, acc[1][mt], 0, 0, 0);
      }
    }
    if (c == 2) __syncthreads();   // all waves' A reads done before V overlays A
    #pragma unroll
    for (int nt = 0; nt < 2; ++nt) {
      float bias = qkv_b[o0 + nt * 16 + l16];
      #pragma unroll
      for (int mt = 0; mt < 4; ++mt)
        #pragma unroll
        for (int r = 0; r < 4; ++r) {
          int m = mt * 16 + quad * 4 + r;           // token (C-layout row)
          int d = nt * 16 + l16;                    // hd channel (C-layout col)
          float v = acc[nt][mt][r] + bias;
          if (c == 0)      *(short*)(qh + qkswz(m, d >> 3) + (d & 7) * 2) = f2bf(v * scale);
          else if (c == 1) *(short*)(kh + qkswz(m, d >> 3) + (d & 7) * 2) = f2bf(v);
          else             *(short*)(vb + pvswz(d, m >> 3) + (m & 7) * 2) = f2bf(v);  // V^T
        }
    }
  }

  // ---- phase 2: S = Q K^T (K-dim = 32 -> single MFMA k-step) ----
  f32x4 s[4][4];
  #pragma unroll
  for (int mt = 0; mt < 4; ++mt)
    #pragma unroll
    for (int nt = 0; nt < 4; ++nt) { f32x4 z = {0.f,0.f,0.f,0.f}; s[mt][nt] = z; }
  {
    short8 aQ[4], bK[4];
    #pragma unroll
    for (int mt = 0; mt < 4; ++mt)
      aQ[mt] = *(const short8*)(qh + qkswz(mt * 16 + l16, quad));
    #pragma unroll
    for (int nt = 0; nt < 4; ++nt)
      bK[nt] = *(const short8*)(kh + qkswz(nt * 16 + l16, quad));
    #pragma unroll
    for (int mt = 0; mt < 4; ++mt)
      #pragma unroll
      for (int nt = 0; nt < 4; ++nt)
        s[mt][nt] = __builtin_amdgcn_mfma_f32_16x16x32_bf16(aQ[mt], bK[nt], s[mt][nt], 0, 0, 0);
  }

  // ---- softmax (in-register, rows live across 16-lane groups) ----
  const int wm = w & (NWM - 1);
  const float* bmh = USE_BM ? bm + (size_t)(wm * NH + h) * (NTOK * NTOK) : nullptr;
  float rinv[4][4];
  #pragma unroll
  for (int mt = 0; mt < 4; ++mt) {
    char* pbase = (mt < 2) ? plo : phi;              // compile-time region select
    #pragma unroll
    for (int r = 0; r < 4; ++r) {
      int m = mt * 16 + quad * 4 + r;
      #pragma unroll
      for (int nt = 0; nt < 4; ++nt) {
        int n = nt * 16 + l16;
        float v = s[mt][nt][r];
        if (n >= NTOK) v = -1e30f;                  // pad key columns -> P = 0
        else if (m < NTOK) {
          if (USE_BM) v += bmh[m * NTOK + n];
          else v += rpb_table[rpb_index[m * NTOK + n] * NH + h]
                  + attn_mask[(wm * NTOK + m) * NTOK + n];
        }
        s[mt][nt][r] = v;
      }
      float mx = fmaxf(fmaxf(s[mt][0][r], s[mt][1][r]), fmaxf(s[mt][2][r], s[mt][3][r]));
      mx = fmaxf(mx, __shfl_xor(mx, 1, 16));
      mx = fmaxf(mx, __shfl_xor(mx, 2, 16));
      mx = fmaxf(mx, __shfl_xor(mx, 4, 16));
      mx = fmaxf(mx, __shfl_xor(mx, 8, 16));
      float t = 0.f;
      #pragma unroll
      for (int nt = 0; nt < 4; ++nt) {
        float p = __expf(s[mt][nt][r] - mx);
        s[mt][nt][r] = p;
        t += p;
      }
      t += __shfl_xor(t, 1, 16);
      t += __shfl_xor(t, 2, 16);
      t += __shfl_xor(t, 4, 16);
      t += __shfl_xor(t, 8, 16);
      rinv[mt][r] = __builtin_amdgcn_rcpf(t);       // ~2^-22 rel err, tol is 1.6e-2
      #pragma unroll
      for (int nt = 0; nt < 4; ++nt) {
        int n = nt * 16 + l16;
        *(short*)(pbase + pvswz(m, n >> 3) + (n & 7) * 2) = f2bf(s[mt][nt][r]);
      }
    }
  }

  // ---- phase 3: Y = P V  (K-dim = 64 tokens -> 2 k-steps) ----
  f32x4 y[2][4];
  #pragma unroll
  for (int dt = 0; dt < 2; ++dt)
    #pragma unroll
    for (int mt = 0; mt < 4; ++mt) { f32x4 z = {0.f,0.f,0.f,0.f}; y[dt][mt] = z; }
  #pragma unroll
  for (int kt = 0; kt < 2; ++kt) {
    short8 aP[4], bV[2];
    #pragma unroll
    for (int mt = 0; mt < 4; ++mt) {
      char* pbase = (mt < 2) ? plo : phi;
      aP[mt] = *(const short8*)(pbase + pvswz(mt * 16 + l16, kt * 4 + quad));
    }
    #pragma unroll
    for (int dt = 0; dt < 2; ++dt)
      bV[dt] = *(const short8*)(vb + pvswz(dt * 16 + l16, kt * 4 + quad));
    #pragma unroll
    for (int dt = 0; dt < 2; ++dt)
      #pragma unroll
      for (int mt = 0; mt < 4; ++mt)
        y[dt][mt] = __builtin_amdgcn_mfma_f32_16x16x32_bf16(aP[mt], bV[dt], y[dt][mt], 0, 0, 0);
  }
  #pragma unroll
  for (int dt = 0; dt < 2; ++dt)
    #pragma unroll
    for (int mt = 0; mt < 4; ++mt)
      #pragma unroll
      for (int r = 0; r < 4; ++r)
        y[dt][mt][r] *= rinv[mt][r];                // softmax denominator

  __syncthreads();   // all P reads done before Y overlays K / P-hi
  #pragma unroll
  for (int dt = 0; dt < 2; ++dt)
    #pragma unroll
    for (int mt = 0; mt < 4; ++mt)
      #pragma unroll
      for (int r = 0; r < 4; ++r) {
        int m = mt * 16 + quad * 4 + r;
        int e = h * HD + dt * 16 + l16;             // output channel 0..127
        *(short*)(yb + aswz(m, e >> 3) + (e & 7) * 2) = f2bf(y[dt][mt][r]);
      }
  __syncthreads();   // Y complete before proj reads it cross-wave

  // ---- phase 4: out = Y proj_w^T + proj_b; wave h handles out cols [32h, 32h+32) ----
  {
    const int o0 = h * 32;
    f32x4 oa[2][4];
    #pragma unroll
    for (int nt = 0; nt < 2; ++nt)
      #pragma unroll
      for (int mt = 0; mt < 4; ++mt) { f32x4 z = {0.f,0.f,0.f,0.f}; oa[nt][mt] = z; }
    #pragma unroll
    for (int ks = 0; ks < 4; ++ks) {
      short8 aY[4];
      #pragma unroll
      for (int mt = 0; mt < 4; ++mt)
        aY[mt] = *(const short8*)(yb + aswz(mt * 16 + l16, ks * 4 + quad));
      short8 b0 = *(const short8*)(wp + (o0 + l16) * DIM + ks * 32 + quad * 8);
      short8 b1 = *(const short8*)(wp + (o0 + 16 + l16) * DIM + ks * 32 + quad * 8);
      #pragma unroll
      for (int mt = 0; mt < 4; ++mt) {
        oa[0][mt] = __builtin_amdgcn_mfma_f32_16x16x32_bf16(aY[mt], b0, oa[0][mt], 0, 0, 0);
        oa[1][mt] = __builtin_amdgcn_mfma_f32_16x16x32_bf16(aY[mt], b1, oa[1][mt], 0, 0, 0);
      }
    }
    float pb0 = proj_b[o0 + l16], pb1 = proj_b[o0 + 16 + l16];
    float* ow = out + (size_t)w * (NTOK * DIM);
    #pragma unroll
    for (int nt = 0; nt < 2; ++nt) {
      float pbv = nt ? pb1 : pb0;
      #pragma unroll
      for (int mt = 0; mt < 4; ++mt)
        #pragma unroll
        for (int r = 0; r < 4; ++r) {
          int m = mt * 16 + quad * 4 + r;
          if (m < NTOK) ow[m * DIM + o0 + nt * 16 + l16] = oa[nt][mt][r] + pbv;
        }
    }
  }
}

extern "C" void kernel_launch(void* const* d_in, const int* in_sizes, int n_in,
                              void* d_out, int out_size, void* d_ws, size_t ws_size,
                              hipStream_t stream) {
  const float* x         = (const float*)d_in[0];
  const float* attn_mask = (const float*)d_in[1];
  const float* qkv_w     = (const float*)d_in[2];
  const float* qkv_b     = (const float*)d_in[3];
  const float* proj_w    = (const float*)d_in[4];
  const float* proj_b    = (const float*)d_in[5];
  const float* rpb_table = (const float*)d_in[6];
  const int*   rpb_index = (const int*)d_in[7];
  float* out = (float*)d_out;

  short* wq = (short*)d_ws;                          // 49152 bf16
  short* wp = wq + 3 * DIM * DIM;                    // 16384 bf16
  float* bmp = (float*)((char*)d_ws + 131072);       // fused bias+mask [64][4][49][49] f32
  size_t need = 131072 + (size_t)NWM * NH * NTOK * NTOK * sizeof(float);

  prep_weights<<<256, 256, 0, stream>>>(qkv_w, proj_w, wq, wp);
  if (ws_size >= need) {
    prep_bm<<<256, 256, 0, stream>>>(attn_mask, rpb_table, rpb_index, bmp);
    swin_attn<true><<<NWIN, 256, 0, stream>>>(x, wq, wp, qkv_b, proj_b, bmp,
                                              rpb_index, rpb_table, attn_mask, out);
  } else {
    swin_attn<false><<<NWIN, 256, 0, stream>>>(x, wq, wp, qkv_b, proj_b, nullptr,
                                               rpb_index, rpb_table, attn_mask, out);
  }
}

// Round 3
// 504.278 us; speedup vs baseline: 1.2609x; 1.0505x over previous
//
#include <hip/hip_runtime.h>
#include <hip/hip_bf16.h>

#define NTOK 49
#define DIM  128
#define NH   4
#define HD   32
#define NWIN 8192
#define NWM  64

typedef short short8 __attribute__((ext_vector_type(8)));
typedef short short4v __attribute__((ext_vector_type(4)));
typedef short short2v __attribute__((ext_vector_type(2)));
typedef float f32x4  __attribute__((ext_vector_type(4)));

// HW RNE f32->bf16 (hipcc emits v_cvt_pk_bf16_f32 for pairs).
__device__ __forceinline__ short f2bf(float f) {
  return __builtin_bit_cast(short, __float2bfloat16(f));
}

// DPP 16-lane rotate (VALU pipe, replaces ds_swizzle shuffles).
#define DPPF(x, ctrl) __builtin_bit_cast(float, __builtin_amdgcn_update_dpp( \
    0, __builtin_bit_cast(int, (x)), (ctrl), 0xf, 0xf, true))
// rotate-based all-reduce over 16 lanes: ror:1, ror:2, ror:4, ror:8

__global__ void prep_weights(const float* __restrict__ qkv_w,
                             const float* __restrict__ proj_w,
                             short* __restrict__ wq, short* __restrict__ wp) {
  int i = blockIdx.x * 256 + threadIdx.x;            // grid covers 49152+16384 exactly
  if (i < 3 * DIM * DIM) {
    wq[i] = f2bf(qkv_w[i]);
  } else {
    // proj_w stored with Y-col permutation so packed Y writes match:
    // within each 32-col head block: e' = 2*(e&15) + ((e>>4)&1)
    int j = i - 3 * DIM * DIM;
    int o = j >> 7, e = j & 127;
    int ep = (e & 96) + ((e & 15) << 1) + ((e >> 4) & 1);
    wp[o * DIM + ep] = f2bf(proj_w[j]);
  }
}

__global__ void prep_bm(const float* __restrict__ attn_mask,
                        const float* __restrict__ rpb_table,
                        const int* __restrict__ rpb_index,
                        float* __restrict__ bm) {
  int wm = blockIdx.x >> 2, h = blockIdx.x & 3;      // 256 blocks = 64 masks x 4 heads
  const float* mrow = attn_mask + wm * (NTOK * NTOK);
  float* dst = bm + blockIdx.x * (NTOK * NTOK);
  for (int i = threadIdx.x; i < NTOK * NTOK; i += 256)
    dst[i] = rpb_table[rpb_index[i] * NH + h] + mrow[i];
}

// LDS layout (49152 B, 3 blocks/CU), identical regions to round 2.
// NEW: contraction dims stored PERMUTED so epilogue writes pack:
//   Q/K cols:  d' = 2*(d&15) + (d>>4)        (both operands of S agree)
//   P cols / V rows(tokens): k' = 4*(k&15) + (k>>4)   (both operands of PV agree)
//   Y cols: per-32 block e' = 2*(e&15) + ((e>>4)&1)   (proj_w permuted to match)
// Read addressing is unchanged (reads 8/16 consecutive permuted slots).
#define A_BASE 0
#define Q_BASE 16384
#define K_BASE 32768
#define LDS_BYTES 49152

// byte-granular swizzled offsets (slot = 16B unit, XOR'd by row bits)
__device__ __forceinline__ int a_byte(int row, int cb) {       // stride 256B, 16 slots
  return row * 256 + ((((cb >> 4) ^ (row & 7)) & 15) << 4) + (cb & 15);
}
__device__ __forceinline__ int qk_byte(int row, int cb) {      // stride 64B, 4 slots
  return row * 64 + ((((cb >> 4) ^ ((row >> 1) & 3)) & 3) << 4) + (cb & 15);
}
__device__ __forceinline__ int pv_byte(int row, int cb) {      // stride 128B, 8 slots
  return row * 128 + ((((cb >> 4) ^ (row & 7)) & 7) << 4) + (cb & 15);
}

template<bool USE_BM>
__global__ void __launch_bounds__(256, 3)
swin_attn(const float* __restrict__ x,
          const short* __restrict__ wq, const short* __restrict__ wp,
          const float* __restrict__ qkv_b, const float* __restrict__ proj_b,
          const float* __restrict__ bm,
          const int* __restrict__ rpb_index, const float* __restrict__ rpb_table,
          const float* __restrict__ attn_mask,
          float* __restrict__ out) {
  __shared__ __align__(16) char smem[LDS_BYTES];
  const int w    = blockIdx.x;
  const int tid  = threadIdx.x;
  const int h    = tid >> 6;          // wave id == head id
  const int lane = tid & 63;
  const int l16  = lane & 15;
  const int quad = lane >> 4;

  char* ab = smem + A_BASE;
  char* qh = smem + Q_BASE + h * 4096;
  char* kh = smem + K_BASE + h * 4096;
  char* vb = smem + A_BASE + h * 4096;     // V overlays A (after c==2 barrier)
  char* yb = smem + K_BASE;                // Y overlays K / P-hi (barrier-protected)
  char* plo = qh;                          // P rows 0-31 overlay Q[h]
  char* phi = kh - 32 * 128;               // P rows 32-63 overlay K[h] (phi + m*128)

  // ---- phase 0: cooperative x -> LDS bf16 (49 rows x 16 8-elem units = 784) ----
  const float* xw = x + (size_t)w * (NTOK * DIM);
  #pragma unroll
  for (int it = 0; it < 4; ++it) {
    int u = tid + it * 256;
    if (u < NTOK * 16) {
      int row = u >> 4, c8 = u & 15;
      const f32x4* p = (const f32x4*)(xw + row * DIM + c8 * 8);
      f32x4 f0 = p[0], f1 = p[1];
      short8 a;
      a[0]=f2bf(f0[0]); a[1]=f2bf(f0[1]); a[2]=f2bf(f0[2]); a[3]=f2bf(f0[3]);
      a[4]=f2bf(f1[0]); a[5]=f2bf(f1[1]); a[6]=f2bf(f1[2]); a[7]=f2bf(f1[3]);
      *(short8*)(ab + a_byte(row, c8 * 16)) = a;
    }
  }
  __syncthreads();

  const float scale = 0.17677669529663687f;  // 32^-0.5, folded into Q

  // ---- phase 1: QKV GEMM. chunk c: 0=Q,1=K,2=V; wave h handles channels c*128+h*32..+32 ----
  #pragma unroll
  for (int c = 0; c < 3; ++c) {
    const int o0 = c * DIM + h * HD;
    f32x4 acc[2][4];
    #pragma unroll
    for (int nt = 0; nt < 2; ++nt)
      #pragma unroll
      for (int mt = 0; mt < 4; ++mt) { f32x4 z = {0.f,0.f,0.f,0.f}; acc[nt][mt] = z; }
    #pragma unroll
    for (int ks = 0; ks < 4; ++ks) {
      short8 b0 = *(const short8*)(wq + (o0 + l16) * DIM + ks * 32 + quad * 8);
      short8 b1 = *(const short8*)(wq + (o0 + 16 + l16) * DIM + ks * 32 + quad * 8);
      short8 aA[4];
      #pragma unroll
      for (int mt = 0; mt < 4; ++mt) {
        int row = mt * 16 + l16; if (row > 48) row = 48;   // A rows 49-63 never written
        aA[mt] = *(const short8*)(ab + a_byte(row, (ks * 4 + quad) * 16));
      }
      #pragma unroll
      for (int mt = 0; mt < 4; ++mt) {
        acc[0][mt] = __builtin_amdgcn_mfma_f32_16x16x32_bf16(aA[mt], b0, acc[0][mt], 0, 0, 0);
        acc[1][mt] = __builtin_amdgcn_mfma_f32_16x16x32_bf16(aA[mt], b1, acc[1][mt], 0, 0, 0);
      }
    }
    if (c == 2) __syncthreads();   // all waves' A reads done before V overlays A
    {
      float bias0 = qkv_b[o0 + l16];
      float bias1 = qkv_b[o0 + 16 + l16];
      #pragma unroll
      for (int mt = 0; mt < 4; ++mt)
        #pragma unroll
        for (int r = 0; r < 4; ++r) {
          int m = mt * 16 + quad * 4 + r;           // token (C-layout row)
          float v0 = acc[0][mt][r] + bias0;         // channel d = l16
          float v1 = acc[1][mt][r] + bias1;         // channel d = l16+16
          if (c == 0) {
            short2v pk; pk[0] = f2bf(v0 * scale); pk[1] = f2bf(v1 * scale);
            *(short2v*)(qh + qk_byte(m, l16 * 4)) = pk;   // permuted cols 2*l16, 2*l16+1
          } else if (c == 1) {
            short2v pk; pk[0] = f2bf(v0); pk[1] = f2bf(v1);
            *(short2v*)(kh + qk_byte(m, l16 * 4)) = pk;
          } else {
            // V^T: row = channel d, col = permuted token k' = 4*(m&15)+(m>>4)
            int cb = (((m & 15) << 2) | (m >> 4)) * 2;
            *(short*)(vb + pv_byte(l16,      cb)) = f2bf(v0);
            *(short*)(vb + pv_byte(l16 + 16, cb)) = f2bf(v1);
          }
        }
    }
  }

  // ---- phase 2: S = Q K^T (contraction over permuted d; both operands permuted) ----
  f32x4 s[4][4];
  #pragma unroll
  for (int mt = 0; mt < 4; ++mt)
    #pragma unroll
    for (int nt = 0; nt < 4; ++nt) { f32x4 z = {0.f,0.f,0.f,0.f}; s[mt][nt] = z; }
  {
    short8 aQ[4], bK[4];
    #pragma unroll
    for (int mt = 0; mt < 4; ++mt)
      aQ[mt] = *(const short8*)(qh + qk_byte(mt * 16 + l16, quad * 16));
    #pragma unroll
    for (int nt = 0; nt < 4; ++nt)
      bK[nt] = *(const short8*)(kh + qk_byte(nt * 16 + l16, quad * 16));
    #pragma unroll
    for (int mt = 0; mt < 4; ++mt)
      #pragma unroll
      for (int nt = 0; nt < 4; ++nt)
        s[mt][nt] = __builtin_amdgcn_mfma_f32_16x16x32_bf16(aQ[mt], bK[nt], s[mt][nt], 0, 0, 0);
  }

  // ---- softmax (in-register; reductions via DPP row_ror, no LDS traffic) ----
  const int wm = w & (NWM - 1);
  const float* bmh = USE_BM ? bm + (size_t)(wm * NH + h) * (NTOK * NTOK) : nullptr;
  float rinv[4][4];
  #pragma unroll
  for (int mt = 0; mt < 4; ++mt) {
    char* pbase = (mt < 2) ? plo : phi;              // compile-time region select
    #pragma unroll
    for (int r = 0; r < 4; ++r) {
      int m = mt * 16 + quad * 4 + r;
      #pragma unroll
      for (int nt = 0; nt < 4; ++nt) {
        int n = nt * 16 + l16;
        float v = s[mt][nt][r];
        if (n >= NTOK) v = -1e30f;                  // pad key columns -> P = 0
        else if (m < NTOK) {
          if (USE_BM) v += bmh[m * NTOK + n];
          else v += rpb_table[rpb_index[m * NTOK + n] * NH + h]
                  + attn_mask[(wm * NTOK + m) * NTOK + n];
        }
        s[mt][nt][r] = v;
      }
      float mx = fmaxf(fmaxf(s[mt][0][r], s[mt][1][r]), fmaxf(s[mt][2][r], s[mt][3][r]));
      mx = fmaxf(mx, DPPF(mx, 0x121));   // ror:1
      mx = fmaxf(mx, DPPF(mx, 0x122));   // ror:2
      mx = fmaxf(mx, DPPF(mx, 0x124));   // ror:4
      mx = fmaxf(mx, DPPF(mx, 0x128));   // ror:8
      float t = 0.f;
      #pragma unroll
      for (int nt = 0; nt < 4; ++nt) {
        float p = __expf(s[mt][nt][r] - mx);
        s[mt][nt][r] = p;
        t += p;
      }
      t += DPPF(t, 0x121);
      t += DPPF(t, 0x122);
      t += DPPF(t, 0x124);
      t += DPPF(t, 0x128);
      rinv[mt][r] = __builtin_amdgcn_rcpf(t);       // ~2^-22 rel err, tol is 1.6e-2
      // P row m, permuted cols 4*l16..4*l16+3 (= original n = l16+16*nt) -> one b64
      short4v pk;
      pk[0] = f2bf(s[mt][0][r]); pk[1] = f2bf(s[mt][1][r]);
      pk[2] = f2bf(s[mt][2][r]); pk[3] = f2bf(s[mt][3][r]);
      *(short4v*)(pbase + pv_byte(m, l16 << 3)) = pk;
    }
  }

  // ---- phase 3: Y = P V  (contraction over permuted token dim; both agree) ----
  f32x4 y[2][4];
  #pragma unroll
  for (int dt = 0; dt < 2; ++dt)
    #pragma unroll
    for (int mt = 0; mt < 4; ++mt) { f32x4 z = {0.f,0.f,0.f,0.f}; y[dt][mt] = z; }
  #pragma unroll
  for (int kt = 0; kt < 2; ++kt) {
    short8 aP[4], bV[2];
    #pragma unroll
    for (int mt = 0; mt < 4; ++mt) {
      char* pbase = (mt < 2) ? plo : phi;
      aP[mt] = *(const short8*)(pbase + pv_byte(mt * 16 + l16, (kt * 4 + quad) * 16));
    }
    #pragma unroll
    for (int dt = 0; dt < 2; ++dt)
      bV[dt] = *(const short8*)(vb + pv_byte(dt * 16 + l16, (kt * 4 + quad) * 16));
    #pragma unroll
    for (int dt = 0; dt < 2; ++dt)
      #pragma unroll
      for (int mt = 0; mt < 4; ++mt)
        y[dt][mt] = __builtin_amdgcn_mfma_f32_16x16x32_bf16(aP[mt], bV[dt], y[dt][mt], 0, 0, 0);
  }
  #pragma unroll
  for (int dt = 0; dt < 2; ++dt)
    #pragma unroll
    for (int mt = 0; mt < 4; ++mt)
      #pragma unroll
      for (int r = 0; r < 4; ++r)
        y[dt][mt][r] *= rinv[mt][r];                // softmax denominator

  __syncthreads();   // all P reads done before Y overlays K / P-hi
  // Y row m, permuted cols within head block: h*32 + 2*l16 + dt -> packed b32
  #pragma unroll
  for (int mt = 0; mt < 4; ++mt)
    #pragma unroll
    for (int r = 0; r < 4; ++r) {
      int m = mt * 16 + quad * 4 + r;
      short2v pk; pk[0] = f2bf(y[0][mt][r]); pk[1] = f2bf(y[1][mt][r]);
      *(short2v*)(yb + a_byte(m, h * 64 + l16 * 4)) = pk;
    }
  __syncthreads();   // Y complete before proj reads it cross-wave

  // ---- phase 4: out = Y proj_w^T + proj_b (wp pre-permuted to match Y cols) ----
  {
    const int o0 = h * 32;
    f32x4 oa[2][4];
    #pragma unroll
    for (int nt = 0; nt < 2; ++nt)
      #pragma unroll
      for (int mt = 0; mt < 4; ++mt) { f32x4 z = {0.f,0.f,0.f,0.f}; oa[nt][mt] = z; }
    #pragma unroll
    for (int ks = 0; ks < 4; ++ks) {
      short8 aY[4];
      #pragma unroll
      for (int mt = 0; mt < 4; ++mt)
        aY[mt] = *(const short8*)(yb + a_byte(mt * 16 + l16, (ks * 4 + quad) * 16));
      short8 b0 = *(const short8*)(wp + (o0 + l16) * DIM + ks * 32 + quad * 8);
      short8 b1 = *(const short8*)(wp + (o0 + 16 + l16) * DIM + ks * 32 + quad * 8);
      #pragma unroll
      for (int mt = 0; mt < 4; ++mt) {
        oa[0][mt] = __builtin_amdgcn_mfma_f32_16x16x32_bf16(aY[mt], b0, oa[0][mt], 0, 0, 0);
        oa[1][mt] = __builtin_amdgcn_mfma_f32_16x16x32_bf16(aY[mt], b1, oa[1][mt], 0, 0, 0);
      }
    }
    float pb0 = proj_b[o0 + l16], pb1 = proj_b[o0 + 16 + l16];
    float* ow = out + (size_t)w * (NTOK * DIM);
    #pragma unroll
    for (int nt = 0; nt < 2; ++nt) {
      float pbv = nt ? pb1 : pb0;
      #pragma unroll
      for (int mt = 0; mt < 4; ++mt)
        #pragma unroll
        for (int r = 0; r < 4; ++r) {
          int m = mt * 16 + quad * 4 + r;
          if (m < NTOK) ow[m * DIM + o0 + nt * 16 + l16] = oa[nt][mt][r] + pbv;
        }
    }
  }
}

extern "C" void kernel_launch(void* const* d_in, const int* in_sizes, int n_in,
                              void* d_out, int out_size, void* d_ws, size_t ws_size,
                              hipStream_t stream) {
  const float* x         = (const float*)d_in[0];
  const float* attn_mask = (const float*)d_in[1];
  const float* qkv_w     = (const float*)d_in[2];
  const float* qkv_b     = (const float*)d_in[3];
  const float* proj_w    = (const float*)d_in[4];
  const float* proj_b    = (const float*)d_in[5];
  const float* rpb_table = (const float*)d_in[6];
  const int*   rpb_index = (const int*)d_in[7];
  float* out = (float*)d_out;

  short* wq = (short*)d_ws;                          // 49152 bf16
  short* wp = wq + 3 * DIM * DIM;                    // 16384 bf16 (Y-col permuted)
  float* bmp = (float*)((char*)d_ws + 131072);       // fused bias+mask [64][4][49][49] f32
  size_t need = 131072 + (size_t)NWM * NH * NTOK * NTOK * sizeof(float);

  prep_weights<<<256, 256, 0, stream>>>(qkv_w, proj_w, wq, wp);
  if (ws_size >= need) {
    prep_bm<<<256, 256, 0, stream>>>(attn_mask, rpb_table, rpb_index, bmp);
    swin_attn<true><<<NWIN, 256, 0, stream>>>(x, wq, wp, qkv_b, proj_b, bmp,
                                              rpb_index, rpb_table, attn_mask, out);
  } else {
    swin_attn<false><<<NWIN, 256, 0, stream>>>(x, wq, wp, qkv_b, proj_b, nullptr,
                                               rpb_index, rpb_table, attn_mask, out);
  }
}

// Round 4
// 471.256 us; speedup vs baseline: 1.3492x; 1.0701x over previous
//
#include <hip/hip_runtime.h>
#include <hip/hip_bf16.h>

#define NTOK 49
#define DIM  128
#define NH   4
#define HD   32
#define NWIN 8192
#define NWM  64

typedef short short8 __attribute__((ext_vector_type(8)));
typedef short short4v __attribute__((ext_vector_type(4)));
typedef short short2v __attribute__((ext_vector_type(2)));
typedef float f32x4  __attribute__((ext_vector_type(4)));

// HW RNE f32->bf16 (hipcc emits v_cvt_pk_bf16_f32 for pairs).
__device__ __forceinline__ short f2bf(float f) {
  return __builtin_bit_cast(short, __float2bfloat16(f));
}

// DPP 16-lane rotate (VALU pipe). Rotate all-reduce: ror 1,2,4,8 within row16.
#define DPPF(x, ctrl) __builtin_bit_cast(float, __builtin_amdgcn_update_dpp( \
    0, __builtin_bit_cast(int, (x)), (ctrl), 0xf, 0xf, true))

__global__ void prep_weights(const float* __restrict__ qkv_w,
                             const float* __restrict__ proj_w,
                             short* __restrict__ wq, short* __restrict__ wp) {
  int i = blockIdx.x * 256 + threadIdx.x;            // grid covers 49152+16384 exactly
  if (i < 3 * DIM * DIM) {
    wq[i] = f2bf(qkv_w[i]);
  } else {
    // proj_w stored with Y-col permutation so packed Y writes match:
    // within each 32-col head block: e' = 2*(e&15) + ((e>>4)&1)
    int j = i - 3 * DIM * DIM;
    int o = j >> 7, e = j & 127;
    int ep = (e & 96) + ((e & 15) << 1) + ((e >> 4) & 1);
    wp[o * DIM + ep] = f2bf(proj_w[j]);
  }
}

// bm layout: [wm][h][49 rows][64 f32-cols], columns PERMUTED n' = 4*(n&15)+(n>>4)
// (matches P/V token permutation). Invalid slots (n>=49) = -1e30 -> exp -> 0,
// so the softmax needs NO n/m guards. 15 extra rows (-1e30) pad the tail so
// kernel reads of rows 49..63 of the last (wm,h) block stay in-bounds.
__global__ void prep_bm(const float* __restrict__ attn_mask,
                        const float* __restrict__ rpb_table,
                        const int* __restrict__ rpb_index,
                        float* __restrict__ bm) {
  int wm = blockIdx.x >> 2, h = blockIdx.x & 3;      // 256 blocks = 64 masks x 4 heads
  const float* mrow = attn_mask + wm * (NTOK * NTOK);
  float* dst = bm + (size_t)blockIdx.x * (NTOK * 64);
  for (int i = threadIdx.x; i < NTOK * 64; i += 256) {
    int m = i >> 6, np = i & 63;
    int n = (np & 3) * 16 + (np >> 2);               // inverse of n' = 4*(n&15)+(n>>4)
    float v = -1e30f;
    if (n < NTOK) v = rpb_table[rpb_index[m * NTOK + n] * NH + h] + mrow[m * NTOK + n];
    dst[i] = v;
  }
  if (blockIdx.x == 255) {                           // tail pad: 15 rows of -1e30
    float* pad = bm + (size_t)NWM * NH * (NTOK * 64);
    for (int i = threadIdx.x; i < 15 * 64; i += 256) pad[i] = -1e30f;
  }
}

// LDS layout (49152 B, 3 blocks/CU) — regions identical to round 3.
#define A_BASE 0
#define Q_BASE 16384
#define K_BASE 32768
#define LDS_BYTES 49152

// byte-granular swizzled offsets (slot = 16B unit, XOR'd by row bits)
__device__ __forceinline__ int a_byte(int row, int cb) {       // stride 256B, 16 slots
  return row * 256 + ((((cb >> 4) ^ (row & 7)) & 15) << 4) + (cb & 15);
}
__device__ __forceinline__ int qk_byte(int row, int cb) {      // stride 64B, 4 slots
  return row * 64 + ((((cb >> 4) ^ ((row >> 1) & 3)) & 3) << 4) + (cb & 15);
}
__device__ __forceinline__ int pv_byte(int row, int cb) {      // stride 128B, 8 slots
  return row * 128 + ((((cb >> 4) ^ (row & 7)) & 7) << 4) + (cb & 15);
}

template<bool USE_BM>
__global__ void __launch_bounds__(256, 3)
swin_attn(const float* __restrict__ x,
          const short* __restrict__ wq, const short* __restrict__ wp,
          const float* __restrict__ qkv_b, const float* __restrict__ proj_b,
          const float* __restrict__ bm,
          const int* __restrict__ rpb_index, const float* __restrict__ rpb_table,
          const float* __restrict__ attn_mask,
          float* __restrict__ out) {
  __shared__ __align__(16) char smem[LDS_BYTES];
  const int w    = blockIdx.x;
  const int tid  = threadIdx.x;
  const int h    = tid >> 6;          // wave id == head id
  const int lane = tid & 63;
  const int l16  = lane & 15;
  const int quad = lane >> 4;

  char* ab = smem + A_BASE;
  char* qh = smem + Q_BASE + h * 4096;
  char* kh = smem + K_BASE + h * 4096;
  char* vb = smem + A_BASE + h * 4096;     // V overlays A (after c==2 barrier)
  char* yb = smem + K_BASE;                // Y overlays K / P-hi (barrier-protected)
  char* plo = qh;                          // P rows 0-31 overlay Q[h]
  char* phi = kh - 32 * 128;               // P rows 32-63 overlay K[h] (phi + m*128)

  // ---- phase 0: cooperative x -> LDS bf16 (49 rows x 16 8-elem units = 784) ----
  const float* xw = x + (size_t)w * (NTOK * DIM);
  #pragma unroll
  for (int it = 0; it < 4; ++it) {
    int u = tid + it * 256;
    if (u < NTOK * 16) {
      int row = u >> 4, c8 = u & 15;
      const f32x4* p = (const f32x4*)(xw + row * DIM + c8 * 8);
      f32x4 f0 = p[0], f1 = p[1];
      short8 a;
      a[0]=f2bf(f0[0]); a[1]=f2bf(f0[1]); a[2]=f2bf(f0[2]); a[3]=f2bf(f0[3]);
      a[4]=f2bf(f1[0]); a[5]=f2bf(f1[1]); a[6]=f2bf(f1[2]); a[7]=f2bf(f1[3]);
      *(short8*)(ab + a_byte(row, c8 * 16)) = a;
    }
  }
  __syncthreads();

  const float scale = 0.17677669529663687f;  // 32^-0.5, folded into Q

  // ---- phase 1: QKV GEMM. chunk c: 0=Q,1=K,2=V; wave h handles channels c*128+h*32..+32 ----
  #pragma unroll
  for (int c = 0; c < 3; ++c) {
    const int o0 = c * DIM + h * HD;
    f32x4 acc[2][4];
    #pragma unroll
    for (int nt = 0; nt < 2; ++nt)
      #pragma unroll
      for (int mt = 0; mt < 4; ++mt) { f32x4 z = {0.f,0.f,0.f,0.f}; acc[nt][mt] = z; }
    #pragma unroll
    for (int ks = 0; ks < 4; ++ks) {
      short8 b0 = *(const short8*)(wq + (o0 + l16) * DIM + ks * 32 + quad * 8);
      short8 b1 = *(const short8*)(wq + (o0 + 16 + l16) * DIM + ks * 32 + quad * 8);
      short8 aA[4];
      #pragma unroll
      for (int mt = 0; mt < 4; ++mt) {
        int row = mt * 16 + l16; if (row > 48) row = 48;   // A rows 49-63 never written
        aA[mt] = *(const short8*)(ab + a_byte(row, (ks * 4 + quad) * 16));
      }
      #pragma unroll
      for (int mt = 0; mt < 4; ++mt) {
        acc[0][mt] = __builtin_amdgcn_mfma_f32_16x16x32_bf16(aA[mt], b0, acc[0][mt], 0, 0, 0);
        acc[1][mt] = __builtin_amdgcn_mfma_f32_16x16x32_bf16(aA[mt], b1, acc[1][mt], 0, 0, 0);
      }
    }
    if (c == 2) __syncthreads();   // all waves' A reads done before V overlays A
    {
      float bias0 = qkv_b[o0 + l16];
      float bias1 = qkv_b[o0 + 16 + l16];
      if (c == 2) {
        // V^T packed: token-permutation makes the 4 mt-values contiguous:
        // permuted col c' = 16*quad + 4*r + mt  (m = mt*16 + quad*4 + r)
        #pragma unroll
        for (int r = 0; r < 4; ++r) {
          short4v pk0, pk1;
          #pragma unroll
          for (int mt = 0; mt < 4; ++mt) {
            pk0[mt] = f2bf(acc[0][mt][r] + bias0);   // channel d = l16
            pk1[mt] = f2bf(acc[1][mt][r] + bias1);   // channel d = l16+16
          }
          *(short4v*)(vb + pv_byte(l16,      quad * 32 + r * 8)) = pk0;
          *(short4v*)(vb + pv_byte(l16 + 16, quad * 32 + r * 8)) = pk1;
        }
      } else {
        #pragma unroll
        for (int mt = 0; mt < 4; ++mt)
          #pragma unroll
          for (int r = 0; r < 4; ++r) {
            int m = mt * 16 + quad * 4 + r;         // token (C-layout row)
            float v0 = acc[0][mt][r] + bias0;       // channel d = l16
            float v1 = acc[1][mt][r] + bias1;       // channel d = l16+16
            short2v pk;
            if (c == 0) { pk[0] = f2bf(v0 * scale); pk[1] = f2bf(v1 * scale); }
            else        { pk[0] = f2bf(v0);         pk[1] = f2bf(v1); }
            *(short2v*)((c == 0 ? qh : kh) + qk_byte(m, l16 * 4)) = pk;
          }
      }
    }
  }

  // ---- phase 2: S = Q K^T (contraction over permuted d; both operands permuted) ----
  f32x4 s[4][4];
  #pragma unroll
  for (int mt = 0; mt < 4; ++mt)
    #pragma unroll
    for (int nt = 0; nt < 4; ++nt) { f32x4 z = {0.f,0.f,0.f,0.f}; s[mt][nt] = z; }
  {
    short8 aQ[4], bK[4];
    #pragma unroll
    for (int mt = 0; mt < 4; ++mt)
      aQ[mt] = *(const short8*)(qh + qk_byte(mt * 16 + l16, quad * 16));
    #pragma unroll
    for (int nt = 0; nt < 4; ++nt)
      bK[nt] = *(const short8*)(kh + qk_byte(nt * 16 + l16, quad * 16));
    #pragma unroll
    for (int mt = 0; mt < 4; ++mt)
      #pragma unroll
      for (int nt = 0; nt < 4; ++nt)
        s[mt][nt] = __builtin_amdgcn_mfma_f32_16x16x32_bf16(aQ[mt], bK[nt], s[mt][nt], 0, 0, 0);
  }

  // ---- fused softmax + PV, per m-tile (all same-wave, in-order LDS) ----
  // No max subtraction: softmax is shift-invariant; scores are O(10), masked
  // entries exp(s-100)->~0, invalid bm slots are -1e30 -> exp -> exact 0.
  const int wm = w & (NWM - 1);
  const float* bmh = USE_BM ? bm + (size_t)(wm * NH + h) * (NTOK * 64) : nullptr;
  float rinv[4][4];
  f32x4 y[2][4];
  #pragma unroll
  for (int dt = 0; dt < 2; ++dt)
    #pragma unroll
    for (int mt = 0; mt < 4; ++mt) { f32x4 z = {0.f,0.f,0.f,0.f}; y[dt][mt] = z; }

  #pragma unroll
  for (int mt = 0; mt < 4; ++mt) {
    char* pbase = (mt < 2) ? plo : phi;              // compile-time region select
    #pragma unroll
    for (int r = 0; r < 4; ++r) {
      int m = mt * 16 + quad * 4 + r;
      float t = 0.f;
      short4v pk;
      if (USE_BM) {
        f32x4 bmv = *(const f32x4*)(bmh + m * 64 + l16 * 4);  // permuted cols 4*l16..+3
        #pragma unroll
        for (int nt = 0; nt < 4; ++nt) {
          float p = __expf(s[mt][nt][r] + bmv[nt]);
          pk[nt] = f2bf(p);
          t += p;
        }
      } else {
        #pragma unroll
        for (int nt = 0; nt < 4; ++nt) {
          int n = nt * 16 + l16;
          float v = s[mt][nt][r];
          if (n >= NTOK) v = -1e30f;
          else if (m < NTOK)
            v += rpb_table[rpb_index[m * NTOK + n] * NH + h]
               + attn_mask[(wm * NTOK + m) * NTOK + n];
          float p = __expf(v);
          pk[nt] = f2bf(p);
          t += p;
        }
      }
      t += DPPF(t, 0x121);   // ror:1
      t += DPPF(t, 0x122);   // ror:2
      t += DPPF(t, 0x124);   // ror:4
      t += DPPF(t, 0x128);   // ror:8
      rinv[mt][r] = __builtin_amdgcn_rcpf(t);       // ~2^-22 rel err, tol is 1.6e-2
      *(short4v*)(pbase + pv_byte(m, l16 << 3)) = pk;   // permuted cols 4*l16..+3
    }
    // PV for this m-tile (reads back the P tile just written; same wave, in-order)
    #pragma unroll
    for (int kt = 0; kt < 2; ++kt) {
      short8 aP = *(const short8*)(pbase + pv_byte(mt * 16 + l16, (kt * 4 + quad) * 16));
      short8 v0 = *(const short8*)(vb + pv_byte(l16,      (kt * 4 + quad) * 16));
      short8 v1 = *(const short8*)(vb + pv_byte(16 + l16, (kt * 4 + quad) * 16));
      y[0][mt] = __builtin_amdgcn_mfma_f32_16x16x32_bf16(aP, v0, y[0][mt], 0, 0, 0);
      y[1][mt] = __builtin_amdgcn_mfma_f32_16x16x32_bf16(aP, v1, y[1][mt], 0, 0, 0);
    }
  }
  #pragma unroll
  for (int dt = 0; dt < 2; ++dt)
    #pragma unroll
    for (int mt = 0; mt < 4; ++mt)
      #pragma unroll
      for (int r = 0; r < 4; ++r)
        y[dt][mt][r] *= rinv[mt][r];                // softmax denominator

  // hoist proj weight fragments (L2) before the barrier convoy
  short8 wb0[4], wb1[4];
  {
    const int o0 = h * 32;
    #pragma unroll
    for (int ks = 0; ks < 4; ++ks) {
      wb0[ks] = *(const short8*)(wp + (o0 + l16) * DIM + ks * 32 + quad * 8);
      wb1[ks] = *(const short8*)(wp + (o0 + 16 + l16) * DIM + ks * 32 + quad * 8);
    }
  }

  __syncthreads();   // all P reads done before Y overlays K / P-hi
  // Y row m, permuted cols within head block: h*32 + 2*l16 + dt -> packed b32
  #pragma unroll
  for (int mt = 0; mt < 4; ++mt)
    #pragma unroll
    for (int r = 0; r < 4; ++r) {
      int m = mt * 16 + quad * 4 + r;
      short2v pk; pk[0] = f2bf(y[0][mt][r]); pk[1] = f2bf(y[1][mt][r]);
      *(short2v*)(yb + a_byte(m, h * 64 + l16 * 4)) = pk;
    }
  __syncthreads();   // Y complete before proj reads it cross-wave

  // ---- phase 4: out = Y proj_w^T + proj_b (wp pre-permuted to match Y cols) ----
  {
    const int o0 = h * 32;
    f32x4 oa[2][4];
    #pragma unroll
    for (int nt = 0; nt < 2; ++nt)
      #pragma unroll
      for (int mt = 0; mt < 4; ++mt) { f32x4 z = {0.f,0.f,0.f,0.f}; oa[nt][mt] = z; }
    #pragma unroll
    for (int ks = 0; ks < 4; ++ks) {
      short8 aY[4];
      #pragma unroll
      for (int mt = 0; mt < 4; ++mt)
        aY[mt] = *(const short8*)(yb + a_byte(mt * 16 + l16, (ks * 4 + quad) * 16));
      #pragma unroll
      for (int mt = 0; mt < 4; ++mt) {
        oa[0][mt] = __builtin_amdgcn_mfma_f32_16x16x32_bf16(aY[mt], wb0[ks], oa[0][mt], 0, 0, 0);
        oa[1][mt] = __builtin_amdgcn_mfma_f32_16x16x32_bf16(aY[mt], wb1[ks], oa[1][mt], 0, 0, 0);
      }
    }
    float pb0 = proj_b[o0 + l16], pb1 = proj_b[o0 + 16 + l16];
    float* ow = out + (size_t)w * (NTOK * DIM);
    #pragma unroll
    for (int nt = 0; nt < 2; ++nt) {
      float pbv = nt ? pb1 : pb0;
      #pragma unroll
      for (int mt = 0; mt < 4; ++mt)
        #pragma unroll
        for (int r = 0; r < 4; ++r) {
          int m = mt * 16 + quad * 4 + r;
          if (m < NTOK) ow[m * DIM + o0 + nt * 16 + l16] = oa[nt][mt][r] + pbv;
        }
    }
  }
}

extern "C" void kernel_launch(void* const* d_in, const int* in_sizes, int n_in,
                              void* d_out, int out_size, void* d_ws, size_t ws_size,
                              hipStream_t stream) {
  const float* x         = (const float*)d_in[0];
  const float* attn_mask = (const float*)d_in[1];
  const float* qkv_w     = (const float*)d_in[2];
  const float* qkv_b     = (const float*)d_in[3];
  const float* proj_w    = (const float*)d_in[4];
  const float* proj_b    = (const float*)d_in[5];
  const float* rpb_table = (const float*)d_in[6];
  const int*   rpb_index = (const int*)d_in[7];
  float* out = (float*)d_out;

  short* wq = (short*)d_ws;                          // 49152 bf16
  short* wp = wq + 3 * DIM * DIM;                    // 16384 bf16 (Y-col permuted)
  float* bmp = (float*)((char*)d_ws + 131072);       // fused bias+mask, permuted cols
  size_t need = 131072 + ((size_t)NWM * NH * NTOK * 64 + 15 * 64) * sizeof(float);

  prep_weights<<<256, 256, 0, stream>>>(qkv_w, proj_w, wq, wp);
  if (ws_size >= need) {
    prep_bm<<<256, 256, 0, stream>>>(attn_mask, rpb_table, rpb_index, bmp);
    swin_attn<true><<<NWIN, 256, 0, stream>>>(x, wq, wp, qkv_b, proj_b, bmp,
                                              rpb_index, rpb_table, attn_mask, out);
  } else {
    swin_attn<false><<<NWIN, 256, 0, stream>>>(x, wq, wp, qkv_b, proj_b, nullptr,
                                               rpb_index, rpb_table, attn_mask, out);
  }
}